// Round 3
// baseline (97.679 us; speedup 1.0000x reference)
//
#include <hip/hip_runtime.h>

// 3-level inverse Haar DWT, fully fused, one pass.
// Input  h  : (16, 192, 64, 64) f32   -> 50.3 MB
// Output out: (16, 3, 512, 512) f32   -> 50.3 MB
//
// Haar synthesis per level:
//   out(2i,2j)  =.5(ll+lh+hl+hh)   out(2i,2j+1)  =.5(ll+lh-hl-hh)
//   out(2i+1,2j)=.5(ll-lh+hl-hh)   out(2i+1,2j+1)=.5(ll-lh-hl+hh)
//
// Each thread produces a 2x8 output patch (rows 2*i0,2*i0+1; cols 8*jo..8*jo+7):
//   LL + 3 yh2 : scalar loads, shared by the 4 row-waves of the block (L1)
//   3 yh1      : float2 loads, shared by 2 row-waves of the block (L1)
//   3 yh0      : float4 loads, unique per thread
// A 256-thread block spans i0 in [4b,4b+4) at fixed i2=b, so ALL coefficient
// sharing is intra-block.

typedef float f32x4 __attribute__((ext_vector_type(4)));

__global__ __launch_bounds__(256) void wave_decoder_kernel(
    const float* __restrict__ h, float* __restrict__ out) {
    const int tid = threadIdx.x;
    const int sp  = blockIdx.x * 256 + tid;   // [0, 16384) per (n,c) image
    const int jo  = sp & 63;                  // octa-col / j2 index [0,64)
    const int i0  = sp >> 6;                  // level-0 row [0,256)
    const int nc  = blockIdx.y;               // n*3 + c
    const int c   = nc % 3;
    const float* __restrict__ hb = h + (size_t)(nc / 3) * (192 * 4096);

    const int i1 = i0 >> 1;                   // [0,128)
    const int i2 = i0 >> 2;                   // [0,64)  == blockIdx.x

    // ---- level 2 (p=1, ch 183+3c+b) + LL (ch c) ----
    const int s2 = i2 * 64 + jo;
    const float llv = hb[c * 4096 + s2];
    const float* __restrict__ y2 = hb + (183 + 3 * c) * 4096 + s2;
    const float lh2 = y2[0];
    const float hl2 = y2[4096];
    const float hh2 = y2[2 * 4096];
    const float sx2 = (i1 & 1) ? -1.f : 1.f;
    const float a2 = llv + sx2 * lh2;
    const float b2 = hl2 + sx2 * hh2;
    const float ll2e = 0.5f * (a2 + b2);      // j1 = 2*jo   (even)
    const float ll2o = 0.5f * (a2 - b2);      // j1 = 2*jo+1 (odd)

    // ---- level 1 (p=2, ch 147+12c+4b+2*ph+pw), j1 in {2jo, 2jo+1} ----
    const int j1 = jo << 1;                   // even
    const int s1 = (i1 & 63) * 64 + (j1 & 63);   // float2-aligned
    const float* __restrict__ y1 =
        hb + (147 + 12 * c + (i1 >> 6) * 2 + (j1 >> 6)) * 4096 + s1;
    const float2 lh1 = *(const float2*)(y1);
    const float2 hl1 = *(const float2*)(y1 + 4 * 4096);
    const float2 hh1 = *(const float2*)(y1 + 8 * 4096);
    const float sx1 = (i0 & 1) ? -1.f : 1.f;
    float ll1[4];
    {
        float t = ll2e + sx1 * lh1.x, u = hl1.x + sx1 * hh1.x;
        ll1[0] = 0.5f * (t + u);  ll1[1] = 0.5f * (t - u);   // j0 = 4jo, 4jo+1
        t = ll2o + sx1 * lh1.y;   u = hl1.y + sx1 * hh1.y;
        ll1[2] = 0.5f * (t + u);  ll1[3] = 0.5f * (t - u);   // j0 = 4jo+2, +3
    }

    // ---- level 0 (p=4, ch 3+48c+16b+4*ph+pw), j0 = 4jo..4jo+3 ----
    const int j0 = jo << 2;
    const int s0 = (i0 & 63) * 64 + (j0 & 63);   // float4-aligned
    const float* __restrict__ y0 =
        hb + (3 + 48 * c + (i0 >> 6) * 4 + (j0 >> 6)) * 4096 + s0;
    const f32x4 lh0 = *(const f32x4*)(y0);
    const f32x4 hl0 = *(const f32x4*)(y0 + 16 * 4096);
    const f32x4 hh0 = *(const f32x4*)(y0 + 32 * 4096);

    f32x4 r00, r01, r10, r11;   // row0 cols 0-3 / 4-7, row1 cols 0-3 / 4-7
    float* r0 = (float*)&r00;   // contiguous pairs: r00,r01 then r10,r11
    float* r1 = (float*)&r10;
    float r0hi[4]; float r1hi[4];
#pragma unroll
    for (int k = 0; k < 4; ++k) {
        const float llk = ll1[k];
        const float lhk = lh0[k], hlk = hl0[k], hhk = hh0[k];
        const float p  = llk + lhk, q  = hlk + hhk;
        const float pm = llk - lhk, qm = hlk - hhk;
        const int lo = 2 * k, hi = 2 * k + 1;
        float* d0 = (k < 2) ? (float*)&r00 : (float*)&r01;
        float* d1 = (k < 2) ? (float*)&r10 : (float*)&r11;
        d0[lo & 3] = 0.5f * (p + q);
        d0[hi & 3] = 0.5f * (p - q);
        d1[lo & 3] = 0.5f * (pm + qm);
        d1[hi & 3] = 0.5f * (pm - qm);
    }
    (void)r0; (void)r1; (void)r0hi; (void)r1hi;

    float* __restrict__ ob =
        out + ((size_t)nc * 512 + (i0 << 1)) * 512 + (jo << 3);
    __builtin_nontemporal_store(r00, (f32x4*)(ob));
    __builtin_nontemporal_store(r01, (f32x4*)(ob + 4));
    __builtin_nontemporal_store(r10, (f32x4*)(ob + 512));
    __builtin_nontemporal_store(r11, (f32x4*)(ob + 516));
}

extern "C" void kernel_launch(void* const* d_in, const int* in_sizes, int n_in,
                              void* d_out, int out_size, void* d_ws, size_t ws_size,
                              hipStream_t stream) {
    const float* h = (const float*)d_in[0];
    float* out = (float*)d_out;
    dim3 grid(64, 48);           // 64 spatial blocks x (n*3+c)
    wave_decoder_kernel<<<grid, dim3(256, 1, 1), 0, stream>>>(h, out);
}